// Round 1
// baseline (32169.022 us; speedup 1.0000x reference)
//
#include <hip/hip_runtime.h>
#include <cstdint>

#define HID    128
#define NB     32            // batch elements per block
#define TPB    256
#define NBLK   2048          // 65536 / NB
#define TSTEPS 30
#define MU_OFF 5898240       // 65536*30*3
#define WS_BIG 65536         // floats per swizzled 512x128 matrix
#define WS_SMALL_OFF (6*WS_BIG)  // 393216

__device__ __forceinline__ float sigm(float v){ return 1.f/(1.f+__expf(-v)); }
__device__ __forceinline__ float tanh_fast(float v){ return 2.f/(1.f+__expf(-2.f*v)) - 1.f; }
// column swizzle for hT[k][e]: quad-level XOR keeps b128 reads aligned, breaks
// the 64-way write conflict (j*32 stride) down to 4-way.
__device__ __forceinline__ int swcol(int e, int k){ return e ^ (k & 28); }

// acc[g][e] += sum_k Wsw(j,k,g) * hT[k][e]  for this thread's 16 elements.
// Wsw layout: float index ((k*128+j)*4 + g). Staged in 16KB chunks (8 k-values).
__device__ __forceinline__ void matvec_acc(float (&acc)[4][16],
    const float* __restrict__ Wsw, const float* hT,
    float* wchunk, int tid, int j, int eg)
{
#pragma unroll 1
  for (int c=0; c<16; ++c){
    __syncthreads();                         // prev chunk's reads done
    {
      const float4* src = (const float4*)(Wsw + c*4096);
      float4* dst = (float4*)wchunk;
#pragma unroll
      for (int it=0; it<4; ++it) dst[it*256 + tid] = src[it*256 + tid];
    }
    __syncthreads();                         // chunk staged
#pragma unroll
    for (int kk=0; kk<8; ++kk){
      const int k  = c*8 + kk;
      const float4 w = ((const float4*)wchunk)[kk*128 + j];   // gates i,f,g,o at (j,k)
      const int kq = (k >> 2) & 7;
#pragma unroll
      for (int e4=0; e4<4; ++e4){
        const int cq = (eg*4 + e4) ^ kq;     // swizzled column quad
        const float4 hv = ((const float4*)(hT + k*NB))[cq];   // broadcast across wave
        acc[0][e4*4+0] += w.x*hv.x; acc[0][e4*4+1] += w.x*hv.y;
        acc[0][e4*4+2] += w.x*hv.z; acc[0][e4*4+3] += w.x*hv.w;
        acc[1][e4*4+0] += w.y*hv.x; acc[1][e4*4+1] += w.y*hv.y;
        acc[1][e4*4+2] += w.y*hv.z; acc[1][e4*4+3] += w.y*hv.w;
        acc[2][e4*4+0] += w.z*hv.x; acc[2][e4*4+1] += w.z*hv.y;
        acc[2][e4*4+2] += w.z*hv.z; acc[2][e4*4+3] += w.z*hv.w;
        acc[3][e4*4+0] += w.w*hv.x; acc[3][e4*4+1] += w.w*hv.y;
        acc[3][e4*4+2] += w.w*hv.z; acc[3][e4*4+3] += w.w*hv.w;
      }
    }
  }
}

__device__ __forceinline__ void cell_update(float (&acc)[4][16], float (&cst)[16],
    float* hTbuf, int j, int eg)
{
  float hnew[16];
#pragma unroll
  for (int e=0;e<16;++e){
    float i_ = sigm(acc[0][e]);
    float f_ = sigm(acc[1][e]);
    float g_ = tanh_fast(acc[2][e]);
    float o_ = sigm(acc[3][e]);
    float c  = f_*cst[e] + i_*g_;
    cst[e]   = c;
    hnew[e]  = o_*tanh_fast(c);
  }
  __syncthreads();                // all reads of old hT finished
#pragma unroll
  for (int e=0;e<16;++e){
    const int ge = eg*16 + e;
    hTbuf[j*NB + swcol(ge, j)] = hnew[e];
  }
  __syncthreads();                // new h visible
}

extern "C" __global__ void __launch_bounds__(TPB)
prep_swizzle(const float* __restrict__ eWhh0, const float* __restrict__ eWih1,
             const float* __restrict__ eWhh1, const float* __restrict__ dWhh0,
             const float* __restrict__ dWih1, const float* __restrict__ dWhh1,
             const float* __restrict__ eWih0, const float* __restrict__ dWih0,
             float* __restrict__ ws)
{
  const int idx = blockIdx.x*TPB + threadIdx.x;
  if (idx < 6*WS_BIG){
    const int m = idx >> 16;
    const int r = idx & 65535;
    const int g = r & 3;
    const int t = r >> 2;
    const int j = t & 127;
    const int k = t >> 7;
    const float* W;
    switch(m){
      case 0: W=eWhh0; break; case 1: W=eWih1; break; case 2: W=eWhh1; break;
      case 3: W=dWhh0; break; case 4: W=dWih1; break; default: W=dWhh1; break;
    }
    ws[idx] = W[((g<<7)|j)*128 + k];
  } else if (idx < 6*WS_BIG + 2*1536){
    const int s = idx - 6*WS_BIG;
    const int which = s / 1536;
    const int r = s % 1536;
    const int j = r / 12, rem = r % 12, g = rem/3, c = rem%3;
    const float* W = which ? dWih0 : eWih0;
    ws[idx] = W[(g*128 + j)*3 + c];
  }
}

extern "C" __global__ void __launch_bounds__(TPB)
lstm_fused(const float* __restrict__ x,
           const float* __restrict__ ws,
           const float* __restrict__ enc_b0, const float* __restrict__ enc_b1,
           const float* __restrict__ dec_b0, const float* __restrict__ dec_b1,
           const float* __restrict__ fc_W,  const float* __restrict__ fc_b,
           float* __restrict__ out)
{
  __shared__ float wchunk[4096];     // 16KB weight chunk
  __shared__ float hT0[HID*NB];      // h layer0, transposed+swizzled
  __shared__ float hT1[HID*NB];      // h layer1
  __shared__ float xT[3*NB];         // layer-0 input (x_t, then fed-back mu)
  __shared__ float fcw[6*HID];

  const int tid = threadIdx.x;
  const int j   = tid & (HID-1);
  const int eg  = tid >> 7;
  const int b0  = blockIdx.x * NB;

  float bE0[4],bE1[4],bD0[4],bD1[4];
#pragma unroll
  for (int g=0; g<4; ++g){
    bE0[g] = enc_b0[g*HID+j];
    bE1[g] = enc_b1[g*HID+j];
    bD0[g] = dec_b0[g*HID+j];
    bD1[g] = dec_b1[g*HID+j];
  }
  float wiE[12], wiD[12];
#pragma unroll
  for (int q=0;q<12;++q){
    wiE[q] = ws[WS_SMALL_OFF + j*12 + q];
    wiD[q] = ws[WS_SMALL_OFF + 1536 + j*12 + q];
  }

  for (int i=tid; i<6*HID;  i+=TPB) fcw[i] = fc_W[i];
  for (int i=tid; i<HID*NB; i+=TPB){ hT0[i]=0.f; hT1[i]=0.f; }

  float c0[16], c1[16];
#pragma unroll
  for (int e=0;e<16;++e){ c0[e]=0.f; c1[e]=0.f; }

  const float* WeWhh0 = ws;
  const float* WeWih1 = ws + 1*WS_BIG;
  const float* WeWhh1 = ws + 2*WS_BIG;
  const float* WdWhh0 = ws + 3*WS_BIG;
  const float* WdWih1 = ws + 4*WS_BIG;
  const float* WdWhh1 = ws + 5*WS_BIG;

  __syncthreads();

  float acc[4][16];

  // -------------------- encoder --------------------
#pragma unroll 1
  for (int t=0; t<TSTEPS; ++t){
    if (tid < 3*NB){
      const int cc = tid >> 5, e = tid & 31;
      xT[cc*NB + e] = x[(b0+e)*90 + t*3 + cc];
    }
    __syncthreads();

    // layer 0
#pragma unroll
    for (int g=0;g<4;++g)
#pragma unroll
      for (int e=0;e<16;++e) acc[g][e] = bE0[g];
#pragma unroll
    for (int e=0;e<16;++e){
      const int ge = eg*16+e;
      const float x0=xT[ge], x1=xT[NB+ge], x2=xT[2*NB+ge];
#pragma unroll
      for (int g=0;g<4;++g)
        acc[g][e] += wiE[g*3]*x0 + wiE[g*3+1]*x1 + wiE[g*3+2]*x2;
    }
    matvec_acc(acc, WeWhh0, hT0, wchunk, tid, j, eg);
    cell_update(acc, c0, hT0, j, eg);

    // layer 1
#pragma unroll
    for (int g=0;g<4;++g)
#pragma unroll
      for (int e=0;e<16;++e) acc[g][e] = bE1[g];
    matvec_acc(acc, WeWih1, hT0, wchunk, tid, j, eg);
    matvec_acc(acc, WeWhh1, hT1, wchunk, tid, j, eg);
    cell_update(acc, c1, hT1, j, eg);
  }
  // xT now holds x[:, 29, :] == decoder's initial input

  // -------------------- decoder --------------------
#pragma unroll 1
  for (int t=0; t<TSTEPS; ++t){
    // layer 0 (input = xT)
#pragma unroll
    for (int g=0;g<4;++g)
#pragma unroll
      for (int e=0;e<16;++e) acc[g][e] = bD0[g];
#pragma unroll
    for (int e=0;e<16;++e){
      const int ge = eg*16+e;
      const float x0=xT[ge], x1=xT[NB+ge], x2=xT[2*NB+ge];
#pragma unroll
      for (int g=0;g<4;++g)
        acc[g][e] += wiD[g*3]*x0 + wiD[g*3+1]*x1 + wiD[g*3+2]*x2;
    }
    matvec_acc(acc, WdWhh0, hT0, wchunk, tid, j, eg);
    cell_update(acc, c0, hT0, j, eg);

    // layer 1
#pragma unroll
    for (int g=0;g<4;++g)
#pragma unroll
      for (int e=0;e<16;++e) acc[g][e] = bD1[g];
    matvec_acc(acc, WdWih1, hT0, wchunk, tid, j, eg);
    matvec_acc(acc, WdWhh1, hT1, wchunk, tid, j, eg);
    cell_update(acc, c1, hT1, j, eg);

    // fc head: stats = h1 @ fc_W^T + fc_b ; mu fed back as next input
    if (tid < 6*NB){
      const int e = tid & 31, oi = tid >> 5;
      float s = fc_b[oi];
#pragma unroll 4
      for (int k=0;k<HID;++k)
        s += fcw[oi*HID + k] * hT1[k*NB + swcol(e,k)];
      const int off = (b0+e)*90 + t*3;
      if (oi < 3){
        out[off + oi] = s;
        xT[oi*NB + e] = s;      // feedback mu
      } else {
        out[MU_OFF + off + (oi-3)] = s;
      }
    }
    __syncthreads();
  }
}

extern "C" void kernel_launch(void* const* d_in, const int* in_sizes, int n_in,
                              void* d_out, int out_size, void* d_ws, size_t ws_size,
                              hipStream_t stream) {
  const float* x        = (const float*)d_in[0];
  const float* enc_Wih0 = (const float*)d_in[1];
  const float* enc_Whh0 = (const float*)d_in[2];
  const float* enc_b0   = (const float*)d_in[3];
  const float* enc_Wih1 = (const float*)d_in[4];
  const float* enc_Whh1 = (const float*)d_in[5];
  const float* enc_b1   = (const float*)d_in[6];
  const float* dec_Wih0 = (const float*)d_in[7];
  const float* dec_Whh0 = (const float*)d_in[8];
  const float* dec_b0   = (const float*)d_in[9];
  const float* dec_Wih1 = (const float*)d_in[10];
  const float* dec_Whh1 = (const float*)d_in[11];
  const float* dec_b1   = (const float*)d_in[12];
  const float* fc_W     = (const float*)d_in[13];
  const float* fc_b     = (const float*)d_in[14];
  float* ws  = (float*)d_ws;
  float* out = (float*)d_out;

  const int prep_elems = 6*WS_BIG + 2*1536;
  const int prep_blocks = (prep_elems + TPB - 1) / TPB;
  prep_swizzle<<<prep_blocks, TPB, 0, stream>>>(
      enc_Whh0, enc_Wih1, enc_Whh1, dec_Whh0, dec_Wih1, dec_Whh1,
      enc_Wih0, dec_Wih0, ws);

  lstm_fused<<<NBLK, TPB, 0, stream>>>(
      x, ws, enc_b0, enc_b1, dec_b0, dec_b1, fc_W, fc_b, out);
}

// Round 2
// 23079.478 us; speedup vs baseline: 1.3938x; 1.3938x over previous
//
#include <hip/hip_runtime.h>
#include <cstdint>

#define HID    128
#define NB     32            // batch elements per block
#define TPB    256
#define NBLK   2048          // 65536 / NB
#define TSTEPS 30
#define MU_OFF 5898240       // 65536*30*3
#define WS_BIG 65536         // floats per swizzled 512x128 matrix
#define WS_SMALL_OFF (6*WS_BIG)  // 393216

__device__ __forceinline__ float sigm(float v){ return 1.f/(1.f+__expf(-v)); }
__device__ __forceinline__ float tanh_fast(float v){ return 2.f/(1.f+__expf(-2.f*v)) - 1.f; }

// h lives in LDS as hT[k][e] with a quad-level XOR swizzle:
//   element (k, e) at  k*32 + (e ^ (k & 28))
// - cell-update writes: thread j writes 4 float4s -> 8 lane-groups cover all
//   32 banks, b128 writes serialize only to the 8-cycle data floor.
// - matvec reads: all 64 lanes read the same address (broadcast, conflict-free).

// acc[g][e] += sum_k W(j,k,g) * hT[k][e].  Weights come STRAIGHT from global
// (L2-resident, coalesced across j-lanes); depth-1 register prefetch.
__device__ __forceinline__ void matvec_acc(float (&acc)[4][16],
    const float4* __restrict__ Wg,   // pre-offset by j; index k*128
    const float* hT, int eg)
{
  float4 w = Wg[0];
#pragma unroll 4
  for (int k=0; k<HID; ++k){
    const float4 wn = Wg[(((k+1)&127))*128];   // prefetch next k (wraps, harmless)
    const int kq = (k>>2)&7;
    const float4* hrow = (const float4*)(hT + k*NB);
#pragma unroll
    for (int e4=0; e4<4; ++e4){
      const float4 hv = hrow[(eg*4+e4) ^ kq];  // wave-broadcast b128
      acc[0][e4*4+0] += w.x*hv.x; acc[0][e4*4+1] += w.x*hv.y;
      acc[0][e4*4+2] += w.x*hv.z; acc[0][e4*4+3] += w.x*hv.w;
      acc[1][e4*4+0] += w.y*hv.x; acc[1][e4*4+1] += w.y*hv.y;
      acc[1][e4*4+2] += w.y*hv.z; acc[1][e4*4+3] += w.y*hv.w;
      acc[2][e4*4+0] += w.z*hv.x; acc[2][e4*4+1] += w.z*hv.y;
      acc[2][e4*4+2] += w.z*hv.z; acc[2][e4*4+3] += w.z*hv.w;
      acc[3][e4*4+0] += w.w*hv.x; acc[3][e4*4+1] += w.w*hv.y;
      acc[3][e4*4+2] += w.w*hv.z; acc[3][e4*4+3] += w.w*hv.w;
    }
    w = wn;
  }
}

__device__ __forceinline__ void cell_update(float (&acc)[4][16], float (&cst)[16],
    float* hTbuf, int j, int eg)
{
  float4 hq[4];
#pragma unroll
  for (int e4=0; e4<4; ++e4){
    float tmp[4];
#pragma unroll
    for (int q=0; q<4; ++q){
      const int e = e4*4+q;
      const float i_ = sigm(acc[0][e]);
      const float f_ = sigm(acc[1][e]);
      const float g_ = tanh_fast(acc[2][e]);
      const float o_ = sigm(acc[3][e]);
      const float c  = f_*cst[e] + i_*g_;
      cst[e] = c;
      tmp[q] = o_*tanh_fast(c);
    }
    hq[e4] = make_float4(tmp[0], tmp[1], tmp[2], tmp[3]);
  }
  __syncthreads();                     // all reads of old h done
  const int jq = (j>>2)&7;
  float4* row = (float4*)(hTbuf + j*NB);
#pragma unroll
  for (int e4=0; e4<4; ++e4)
    row[(eg*4+e4) ^ jq] = hq[e4];      // b128, bank-floor writes
  __syncthreads();                     // new h visible
}

extern "C" __global__ void __launch_bounds__(TPB)
prep_swizzle(const float* __restrict__ eWhh0, const float* __restrict__ eWih1,
             const float* __restrict__ eWhh1, const float* __restrict__ dWhh0,
             const float* __restrict__ dWih1, const float* __restrict__ dWhh1,
             const float* __restrict__ eWih0, const float* __restrict__ dWih0,
             float* __restrict__ ws)
{
  const int idx = blockIdx.x*TPB + threadIdx.x;
  if (idx < 6*WS_BIG){
    const int m = idx >> 16;
    const int r = idx & 65535;
    const int g = r & 3;
    const int t = r >> 2;
    const int j = t & 127;
    const int k = t >> 7;
    const float* W;
    switch(m){
      case 0: W=eWhh0; break; case 1: W=eWih1; break; case 2: W=eWhh1; break;
      case 3: W=dWhh0; break; case 4: W=dWih1; break; default: W=dWhh1; break;
    }
    ws[idx] = W[((g<<7)|j)*128 + k];
  } else if (idx < 6*WS_BIG + 2*1536){
    const int s = idx - 6*WS_BIG;
    const int which = s / 1536;
    const int r = s % 1536;
    const int j = r / 12, rem = r % 12, g = rem/3, c = rem%3;
    const float* W = which ? dWih0 : eWih0;
    ws[idx] = W[(g*128 + j)*3 + c];
  }
}

extern "C" __global__ void __launch_bounds__(TPB, 3)
lstm_fused(const float* __restrict__ x,
           const float* __restrict__ ws,
           const float* __restrict__ enc_b0, const float* __restrict__ enc_b1,
           const float* __restrict__ dec_b0, const float* __restrict__ dec_b1,
           const float* __restrict__ fc_W,  const float* __restrict__ fc_b,
           float* __restrict__ out)
{
  __shared__ float hT0[HID*NB];      // 16 KB, swizzled transpose of h layer0
  __shared__ float hT1[HID*NB];      // 16 KB
  __shared__ float xall[TSTEPS*3*NB];// 11.25 KB, x pre-staged [t][c][e]
  __shared__ float xT[3*NB];         // decoder feedback input
  __shared__ float fcw[6*HID];

  const int tid = threadIdx.x;
  const int j   = tid & (HID-1);
  const int eg  = tid >> 7;
  const int b0  = blockIdx.x * NB;

  float bE0[4],bE1[4],bD0[4],bD1[4];
#pragma unroll
  for (int g=0; g<4; ++g){
    bE0[g] = enc_b0[g*HID+j];
    bE1[g] = enc_b1[g*HID+j];
    bD0[g] = dec_b0[g*HID+j];
    bD1[g] = dec_b1[g*HID+j];
  }
  float wiE[12], wiD[12];
#pragma unroll
  for (int q=0;q<12;++q){
    wiE[q] = ws[WS_SMALL_OFF + j*12 + q];
    wiD[q] = ws[WS_SMALL_OFF + 1536 + j*12 + q];
  }

  for (int i=tid; i<6*HID;  i+=TPB) fcw[i] = fc_W[i];
  for (int i=tid; i<HID*NB; i+=TPB){ hT0[i]=0.f; hT1[i]=0.f; }
  for (int i=tid; i<TSTEPS*3*NB; i+=TPB){
    const int t = i/96, r = i%96, c = r>>5, e = r&31;
    xall[i] = x[(b0+e)*90 + t*3 + c];
  }

  float c0[16], c1[16];
#pragma unroll
  for (int e=0;e<16;++e){ c0[e]=0.f; c1[e]=0.f; }

  const float4* WeWhh0 = (const float4*)(ws            ) + j;
  const float4* WeWih1 = (const float4*)(ws + 1*WS_BIG ) + j;
  const float4* WeWhh1 = (const float4*)(ws + 2*WS_BIG ) + j;
  const float4* WdWhh0 = (const float4*)(ws + 3*WS_BIG ) + j;
  const float4* WdWih1 = (const float4*)(ws + 4*WS_BIG ) + j;
  const float4* WdWhh1 = (const float4*)(ws + 5*WS_BIG ) + j;

  __syncthreads();

  float acc[4][16];

  // -------------------- encoder --------------------
#pragma unroll 1
  for (int t=0; t<TSTEPS; ++t){
    const float* xp = xall + t*96;

    // layer 0
#pragma unroll
    for (int g=0;g<4;++g)
#pragma unroll
      for (int e=0;e<16;++e) acc[g][e] = bE0[g];
#pragma unroll
    for (int e=0;e<16;++e){
      const int ge = eg*16+e;
      const float x0=xp[ge], x1=xp[NB+ge], x2=xp[2*NB+ge];
#pragma unroll
      for (int g=0;g<4;++g)
        acc[g][e] += wiE[g*3]*x0 + wiE[g*3+1]*x1 + wiE[g*3+2]*x2;
    }
    matvec_acc(acc, WeWhh0, hT0, eg);
    cell_update(acc, c0, hT0, j, eg);

    // layer 1
#pragma unroll
    for (int g=0;g<4;++g)
#pragma unroll
      for (int e=0;e<16;++e) acc[g][e] = bE1[g];
    matvec_acc(acc, WeWih1, hT0, eg);
    matvec_acc(acc, WeWhh1, hT1, eg);
    cell_update(acc, c1, hT1, j, eg);
  }

  // decoder initial input = x[:, 29, :]
  if (tid < 3*NB) xT[tid] = xall[29*96 + tid];
  __syncthreads();

  // -------------------- decoder --------------------
#pragma unroll 1
  for (int t=0; t<TSTEPS; ++t){
    // layer 0 (input = xT)
#pragma unroll
    for (int g=0;g<4;++g)
#pragma unroll
      for (int e=0;e<16;++e) acc[g][e] = bD0[g];
#pragma unroll
    for (int e=0;e<16;++e){
      const int ge = eg*16+e;
      const float x0=xT[ge], x1=xT[NB+ge], x2=xT[2*NB+ge];
#pragma unroll
      for (int g=0;g<4;++g)
        acc[g][e] += wiD[g*3]*x0 + wiD[g*3+1]*x1 + wiD[g*3+2]*x2;
    }
    matvec_acc(acc, WdWhh0, hT0, eg);
    cell_update(acc, c0, hT0, j, eg);

    // layer 1
#pragma unroll
    for (int g=0;g<4;++g)
#pragma unroll
      for (int e=0;e<16;++e) acc[g][e] = bD1[g];
    matvec_acc(acc, WdWih1, hT0, eg);
    matvec_acc(acc, WdWhh1, hT1, eg);
    cell_update(acc, c1, hT1, j, eg);

    // fc head: stats = h1 @ fc_W^T + fc_b ; mu fed back as next input
    if (tid < 6*NB){
      const int e = tid & 31, oi = tid >> 5;
      float s = fc_b[oi];
#pragma unroll 8
      for (int k=0;k<HID;++k)
        s += fcw[oi*HID + k] * hT1[k*NB + (e ^ (k&28))];
      const int off = (b0+e)*90 + t*3;
      if (oi < 3){
        out[off + oi] = s;
        xT[oi*NB + e] = s;      // feedback mu
      } else {
        out[MU_OFF + off + (oi-3)] = s;
      }
    }
    __syncthreads();
  }
}

extern "C" void kernel_launch(void* const* d_in, const int* in_sizes, int n_in,
                              void* d_out, int out_size, void* d_ws, size_t ws_size,
                              hipStream_t stream) {
  const float* x        = (const float*)d_in[0];
  const float* enc_Wih0 = (const float*)d_in[1];
  const float* enc_Whh0 = (const float*)d_in[2];
  const float* enc_b0   = (const float*)d_in[3];
  const float* enc_Wih1 = (const float*)d_in[4];
  const float* enc_Whh1 = (const float*)d_in[5];
  const float* enc_b1   = (const float*)d_in[6];
  const float* dec_Wih0 = (const float*)d_in[7];
  const float* dec_Whh0 = (const float*)d_in[8];
  const float* dec_b0   = (const float*)d_in[9];
  const float* dec_Wih1 = (const float*)d_in[10];
  const float* dec_Whh1 = (const float*)d_in[11];
  const float* dec_b1   = (const float*)d_in[12];
  const float* fc_W     = (const float*)d_in[13];
  const float* fc_b     = (const float*)d_in[14];
  float* ws  = (float*)d_ws;
  float* out = (float*)d_out;

  const int prep_elems = 6*WS_BIG + 2*1536;
  const int prep_blocks = (prep_elems + TPB - 1) / TPB;
  prep_swizzle<<<prep_blocks, TPB, 0, stream>>>(
      enc_Whh0, enc_Wih1, enc_Whh1, dec_Whh0, dec_Wih1, dec_Whh1,
      enc_Wih0, dec_Wih0, ws);

  lstm_fused<<<NBLK, TPB, 0, stream>>>(
      x, ws, enc_b0, enc_b1, dec_b0, dec_b1, fc_W, fc_b, out);
}

// Round 3
// 9056.564 us; speedup vs baseline: 3.5520x; 2.5484x over previous
//
#include <hip/hip_runtime.h>
#include <cstdint>

typedef short short8  __attribute__((ext_vector_type(8)));
typedef float floatx4 __attribute__((ext_vector_type(4)));

#define HID    128
#define NB     64
#define TPB    512
#define NBLK   1024          // 65536 / 64
#define TSTEPS 30
#define MU_OFF 5898240       // 65536*30*3

// ws layout (bf16 units): A-fragment-swizzled weight arrays, hi then lo per set
#define L0_SZ  81920         // 512*160  (K-ext: [Whh(128)|Wih0(3)|0(29)])
#define L1_SZ  131072        // 512*256  (K-ext: [Wih1(128)|Whh1(128)])
#define ENC0_HI 0
#define ENC0_LO 81920
#define ENC1_HI 163840
#define ENC1_LO 294912
#define DEC0_HI 425984
#define DEC0_LO 507904
#define DEC1_HI 589824
#define DEC1_LO 720896
#define WS_TOT  851968       // bf16 elements = 1.70 MB

#define S0 192               // hB0 row stride (bf16): 20 k-blocks + XOR headroom -> 24
#define S1 128               // hB1 row stride: 16 k-blocks, XOR stays in range

__device__ __forceinline__ float sigm(float v){ return 1.f/(1.f+__expf(-v)); }
__device__ __forceinline__ float tanh_fast(float v){ return 2.f/(1.f+__expf(-2.f*v)) - 1.f; }

__device__ __forceinline__ unsigned short f2bf(float f){
  unsigned u = __float_as_uint(f);
  u = (u + 0x7FFF + ((u>>16)&1)) >> 16;     // RNE; inputs finite
  return (unsigned short)u;
}
__device__ __forceinline__ float bf2f(unsigned short b){
  return __uint_as_float(((unsigned)b)<<16);
}

// ---------------- prep: swizzle weights into A-fragment order, bf16 hi/lo ----
// A-frag element (mt, kt, lane l, jj):  A[mt*16 + (l&15)][kt*32 + ((l>>4)&3)*8 + jj]
// stored at ((mt*KT + kt)*64 + l)*8 + jj   -> consumer does 1 coalesced b128/lane
extern "C" __global__ void __launch_bounds__(256)
prep_frag(const float* __restrict__ eWih0, const float* __restrict__ eWhh0,
          const float* __restrict__ eWih1, const float* __restrict__ eWhh1,
          const float* __restrict__ dWih0, const float* __restrict__ dWhh0,
          const float* __restrict__ dWih1, const float* __restrict__ dWhh1,
          unsigned short* __restrict__ ws)
{
  const int idx = blockIdx.x*256 + threadIdx.x;   // one thread -> one (hi,lo) pair
  int i2, hi_base, lo_base, KT;
  const float* Wa; const float* Wb;
  if (idx < L0_SZ)                { i2=idx;                 hi_base=ENC0_HI; lo_base=ENC0_LO; Wa=eWhh0; Wb=eWih0; KT=5; }
  else if (idx < L0_SZ+L1_SZ)     { i2=idx-L0_SZ;           hi_base=ENC1_HI; lo_base=ENC1_LO; Wa=eWih1; Wb=eWhh1; KT=8; }
  else if (idx < 2*L0_SZ+L1_SZ)   { i2=idx-(L0_SZ+L1_SZ);   hi_base=DEC0_HI; lo_base=DEC0_LO; Wa=dWhh0; Wb=dWih0; KT=5; }
  else                            { i2=idx-(2*L0_SZ+L1_SZ); hi_base=DEC1_HI; lo_base=DEC1_LO; Wa=dWih1; Wb=dWhh1; KT=8; }
  const int jj = i2 & 7, l = (i2>>3)&63, tk = i2>>9;
  const int kt = (KT==5) ? (tk%5) : (tk&7);
  const int mt = (KT==5) ? (tk/5) : (tk>>3);
  const int row = mt*16 + (l&15);
  const int k   = kt*32 + ((l>>4)&3)*8 + jj;
  float w;
  if (KT==5) w = (k<128) ? Wa[row*128+k] : ((k<131) ? Wb[row*3 + (k-128)] : 0.f);
  else       w = (k<128) ? Wa[row*128+k] : Wb[row*128 + (k-128)];
  const unsigned short hi = f2bf(w);
  ws[hi_base + i2] = hi;
  ws[lo_base + i2] = f2bf(w - bf2f(hi));
}

// ---------------- fused LSTM: all big matvecs on MFMA ------------------------
extern "C" __global__ void __launch_bounds__(TPB)
lstm_mfma(const float* __restrict__ x,
          const unsigned short* __restrict__ wf,
          const float* __restrict__ enc_b0, const float* __restrict__ enc_b1,
          const float* __restrict__ dec_b0, const float* __restrict__ dec_b1,
          const float* __restrict__ fc_W,  const float* __restrict__ fc_b,
          float* __restrict__ out)
{
  // h in B-frag-ready layout: row n (batch), k contiguous, 8-elem blocks
  // XOR-swizzled: element (n,k) at n*S + ((k>>3)^(n&7))*8 + (k&7)
  __shared__ unsigned short h0h[NB*S0], h0l[NB*S0];   // K=160 region (x rows 128-130)
  __shared__ unsigned short h1h[NB*S1], h1l[NB*S1];
  __shared__ float bias[4*512];
  __shared__ float fcw[6*HID];
  __shared__ float fcb[8];

  const int tid  = threadIdx.x;
  const int w    = tid>>6, l = tid&63;
  const int quad = (l>>4)&3, n15 = l&15, q7 = n15&7;
  const int b0   = blockIdx.x*NB;
  const int jbase= w*16;
  const int mtv[4] = {w, 8+w, 16+w, 24+w};   // i,f,g,o tiles for j-slice [16w,16w+16)

  for (int i=tid;i<512;i+=TPB){
    bias[i]=enc_b0[i]; bias[512+i]=enc_b1[i];
    bias[1024+i]=dec_b0[i]; bias[1536+i]=dec_b1[i];
  }
  for (int i=tid;i<6*HID;i+=TPB) fcw[i]=fc_W[i];
  if (tid<6) fcb[tid]=fc_b[tid];
  for (int i=tid;i<NB*S0;i+=TPB){ h0h[i]=0; h0l[i]=0; }
  for (int i=tid;i<NB*S1;i+=TPB){ h1h[i]=0; h1l[i]=0; }
  __syncthreads();

  auto write_x = [&](int t){
    if (tid < 192){
      const int n = tid & 63, c = tid >> 6;
      const float v = x[(size_t)(b0+n)*90 + t*3 + c];
      const int k = 128 + c;
      const int idx = n*S0 + ((((k>>3))^(n&7))<<3) + (k&7);
      const unsigned short hi = f2bf(v);
      h0h[idx] = hi; h0l[idx] = f2bf(v - bf2f(hi));
    }
  };
  write_x(0);
  __syncthreads();

  floatx4 acc[4][4];
  float c0[4][4], c1[4][4];
#pragma unroll
  for (int a=0;a<4;a++)
#pragma unroll
    for (int b=0;b<4;b++){ c0[a][b]=0.f; c1[a][b]=0.f; }

  // layer0 matvec: K=160 (5 kt), B entirely from hB0 (h rows + x rows)
  auto matvec0 = [&](const unsigned short* Ahi, const unsigned short* Alo){
    const floatx4 z = {0.f,0.f,0.f,0.f};
#pragma unroll
    for (int g=0;g<4;g++)
#pragma unroll
      for (int nt=0;nt<4;nt++) acc[g][nt]=z;
    short8 ah[4], al[4], ahn[4], aln[4];
#pragma unroll
    for (int g=0;g<4;g++){
      const int ao = ((mtv[g]*5)*64 + l)*8;
      ah[g] = *(const short8*)(Ahi + ao);
      al[g] = *(const short8*)(Alo + ao);
    }
#pragma unroll 1
    for (int kt=0;kt<5;kt++){
      if (kt<4){
#pragma unroll
        for (int g=0;g<4;g++){
          const int ao = ((mtv[g]*5 + kt+1)*64 + l)*8;
          ahn[g] = *(const short8*)(Ahi + ao);
          aln[g] = *(const short8*)(Alo + ao);
        }
      }
      const int bo = (((kt*4+quad)^q7)<<3);
      short8 bh[4], bl[4];
#pragma unroll
      for (int nt=0;nt<4;nt++){
        const int ro = (nt*16+n15)*S0 + bo;
        bh[nt] = *(const short8*)(h0h + ro);
        bl[nt] = *(const short8*)(h0l + ro);
      }
#pragma unroll
      for (int g=0;g<4;g++)
#pragma unroll
        for (int nt=0;nt<4;nt++){
          acc[g][nt] = __builtin_amdgcn_mfma_f32_16x16x32_bf16(ah[g], bh[nt], acc[g][nt],0,0,0);
          acc[g][nt] = __builtin_amdgcn_mfma_f32_16x16x32_bf16(ah[g], bl[nt], acc[g][nt],0,0,0);
          acc[g][nt] = __builtin_amdgcn_mfma_f32_16x16x32_bf16(al[g], bh[nt], acc[g][nt],0,0,0);
        }
#pragma unroll
      for (int g=0;g<4;g++){ ah[g]=ahn[g]; al[g]=aln[g]; }
    }
  };

  // layer1 matvec: K=256 (8 kt): kt<4 -> hB0 (h0), kt>=4 -> hB1 (h1)
  auto matvec1 = [&](const unsigned short* Ahi, const unsigned short* Alo){
    const floatx4 z = {0.f,0.f,0.f,0.f};
#pragma unroll
    for (int g=0;g<4;g++)
#pragma unroll
      for (int nt=0;nt<4;nt++) acc[g][nt]=z;
    short8 ah[4], al[4], ahn[4], aln[4];
#pragma unroll
    for (int g=0;g<4;g++){
      const int ao = ((mtv[g]*8)*64 + l)*8;
      ah[g] = *(const short8*)(Ahi + ao);
      al[g] = *(const short8*)(Alo + ao);
    }
#pragma unroll 1
    for (int kt=0;kt<8;kt++){
      if (kt<7){
#pragma unroll
        for (int g=0;g<4;g++){
          const int ao = ((mtv[g]*8 + kt+1)*64 + l)*8;
          ahn[g] = *(const short8*)(Ahi + ao);
          aln[g] = *(const short8*)(Alo + ao);
        }
      }
      const unsigned short* Bh = (kt<4) ? h0h : h1h;
      const unsigned short* Bl = (kt<4) ? h0l : h1l;
      const int SS  = (kt<4) ? S0 : S1;
      const int ktl = kt & 3;
      const int bo  = (((ktl*4+quad)^q7)<<3);
      short8 bh[4], bl[4];
#pragma unroll
      for (int nt=0;nt<4;nt++){
        const int ro = (nt*16+n15)*SS + bo;
        bh[nt] = *(const short8*)(Bh + ro);
        bl[nt] = *(const short8*)(Bl + ro);
      }
#pragma unroll
      for (int g=0;g<4;g++)
#pragma unroll
        for (int nt=0;nt<4;nt++){
          acc[g][nt] = __builtin_amdgcn_mfma_f32_16x16x32_bf16(ah[g], bh[nt], acc[g][nt],0,0,0);
          acc[g][nt] = __builtin_amdgcn_mfma_f32_16x16x32_bf16(ah[g], bl[nt], acc[g][nt],0,0,0);
          acc[g][nt] = __builtin_amdgcn_mfma_f32_16x16x32_bf16(al[g], bh[nt], acc[g][nt],0,0,0);
        }
#pragma unroll
      for (int g=0;g<4;g++){ ah[g]=ahn[g]; al[g]=aln[g]; }
    }
  };

  // in-register cell update; caller must barrier AFTER (writes -> visibility)
  auto cell_update = [&](float (&cst)[4][4], int boff,
                         unsigned short* Hh, unsigned short* Hl, int SS){
    float hv[4][4];
#pragma unroll
    for (int nt=0;nt<4;nt++)
#pragma unroll
      for (int r=0;r<4;r++){
        const int j = jbase + quad*4 + r;
        const float i_ = sigm(acc[0][nt][r] + bias[boff       + j]);
        const float f_ = sigm(acc[1][nt][r] + bias[boff + 128 + j]);
        const float g_ = tanh_fast(acc[2][nt][r] + bias[boff + 256 + j]);
        const float o_ = sigm(acc[3][nt][r] + bias[boff + 384 + j]);
        const float c  = f_*cst[nt][r] + i_*g_;
        cst[nt][r] = c;
        hv[nt][r]  = o_*tanh_fast(c);
      }
    __syncthreads();                 // all waves done READING old h
#pragma unroll
    for (int nt=0;nt<4;nt++)
#pragma unroll
      for (int r=0;r<4;r++){
        const int j = jbase + quad*4 + r;
        const int n = nt*16 + n15;
        const int idx = n*SS + ((((j>>3))^(n&7))<<3) + (j&7);
        const unsigned short hi = f2bf(hv[nt][r]);
        Hh[idx] = hi;
        Hl[idx] = f2bf(hv[nt][r] - bf2f(hi));
      }
  };

  // -------------------- encoder --------------------
#pragma unroll 1
  for (int t=0; t<TSTEPS; ++t){
    matvec0(wf+ENC0_HI, wf+ENC0_LO);
    cell_update(c0, 0, h0h, h0l, S0);
    if (t+1 < TSTEPS) write_x(t+1);      // safe: after barrier, before next read
    __syncthreads();
    matvec1(wf+ENC1_HI, wf+ENC1_LO);
    cell_update(c1, 512, h1h, h1l, S1);
    __syncthreads();
  }
  // hB0 x-rows now hold x[:,29,:] == decoder's initial input

  // -------------------- decoder --------------------
#pragma unroll 1
  for (int t=0; t<TSTEPS; ++t){
    matvec0(wf+DEC0_HI, wf+DEC0_LO);
    cell_update(c0, 1024, h0h, h0l, S0);
    __syncthreads();
    matvec1(wf+DEC1_HI, wf+DEC1_LO);
    cell_update(c1, 1536, h1h, h1l, S1);
    __syncthreads();

    // FC head: stats[6][64] = fcW @ h1 + fcb; mu fed back into hB0 x-rows
    if (tid < 384){
      const int n = tid & 63, oi = tid >> 6;
      float s = fcb[oi];
#pragma unroll 4
      for (int blk=0; blk<16; ++blk){
        const int ro = n*S1 + ((blk^(n&7))<<3);
        const short8 hh = *(const short8*)(h1h + ro);
        const short8 hl = *(const short8*)(h1l + ro);
#pragma unroll
        for (int jj=0;jj<8;++jj)
          s += fcw[oi*HID + blk*8 + jj] *
               (bf2f((unsigned short)hh[jj]) + bf2f((unsigned short)hl[jj]));
      }
      const size_t off = (size_t)(b0+n)*90 + (size_t)t*3;
      if (oi < 3){
        out[off + oi] = s;
        const int k = 128 + oi;
        const int idx = n*S0 + ((((k>>3))^(n&7))<<3) + (k&7);
        const unsigned short hi = f2bf(s);
        h0h[idx] = hi; h0l[idx] = f2bf(s - bf2f(hi));
      } else {
        out[MU_OFF + off + (oi-3)] = s;
      }
    }
    __syncthreads();
  }
}

extern "C" void kernel_launch(void* const* d_in, const int* in_sizes, int n_in,
                              void* d_out, int out_size, void* d_ws, size_t ws_size,
                              hipStream_t stream) {
  const float* x        = (const float*)d_in[0];
  const float* enc_Wih0 = (const float*)d_in[1];
  const float* enc_Whh0 = (const float*)d_in[2];
  const float* enc_b0   = (const float*)d_in[3];
  const float* enc_Wih1 = (const float*)d_in[4];
  const float* enc_Whh1 = (const float*)d_in[5];
  const float* enc_b1   = (const float*)d_in[6];
  const float* dec_Wih0 = (const float*)d_in[7];
  const float* dec_Whh0 = (const float*)d_in[8];
  const float* dec_b0   = (const float*)d_in[9];
  const float* dec_Wih1 = (const float*)d_in[10];
  const float* dec_Whh1 = (const float*)d_in[11];
  const float* dec_b1   = (const float*)d_in[12];
  const float* fc_W     = (const float*)d_in[13];
  const float* fc_b     = (const float*)d_in[14];
  unsigned short* ws = (unsigned short*)d_ws;
  float* out = (float*)d_out;

  // 425,984 (hi,lo) pairs -> exactly 1664 blocks of 256
  prep_frag<<<1664, 256, 0, stream>>>(
      enc_Wih0, enc_Whh0, enc_Wih1, enc_Whh1,
      dec_Wih0, dec_Whh0, dec_Wih1, dec_Whh1, ws);

  lstm_mfma<<<NBLK, TPB, 0, stream>>>(
      x, ws, enc_b0, enc_b1, dec_b0, dec_b1, fc_W, fc_b, out);
}

// Round 4
// 6444.408 us; speedup vs baseline: 4.9918x; 1.4053x over previous
//
#include <hip/hip_runtime.h>
#include <cstdint>

typedef short short8  __attribute__((ext_vector_type(8)));
typedef unsigned short ushort4v __attribute__((ext_vector_type(4)));
typedef float floatx4 __attribute__((ext_vector_type(4)));

#define HID    128
#define NB     32
#define TPB    256
#define NBLK   2048          // 65536 / 32
#define TSTEPS 30
#define MU_OFF 5898240       // 65536*30*3

// ws layout (bf16 units): A-fragment-swizzled weight arrays, hi then lo per set
#define L0_SZ  81920         // 512*160  (K-ext: [Whh(128)|Wih0(3)|0(29)])
#define L1_SZ  131072        // 512*256  (K-ext: [Wih1(128)|Whh1(128)])
#define ENC0_HI 0
#define ENC0_LO 81920
#define ENC1_HI 163840
#define ENC1_LO 294912
#define DEC0_HI 425984
#define DEC0_LO 507904
#define DEC1_HI 589824
#define DEC1_LO 720896

#define S0 192               // h0 row stride (bf16): 20 k-blocks + XOR headroom -> 24
#define S1 128               // h1 row stride: 16 k-blocks

__device__ __forceinline__ float sigm(float v){ return 1.f/(1.f+__expf(-v)); }
__device__ __forceinline__ float tanh_fast(float v){ return 2.f/(1.f+__expf(-2.f*v)) - 1.f; }

__device__ __forceinline__ unsigned short f2bf(float f){
  unsigned u = __float_as_uint(f);
  u = (u + 0x7FFF + ((u>>16)&1)) >> 16;     // RNE; inputs finite
  return (unsigned short)u;
}
__device__ __forceinline__ float bf2f(unsigned short b){
  return __uint_as_float(((unsigned)b)<<16);
}

// ---------------- prep: swizzle weights into A-fragment order, bf16 hi/lo ----
// A-frag element (mt, kt, lane l, jj):  A[mt*16 + (l&15)][kt*32 + ((l>>4)&3)*8 + jj]
// stored at ((mt*KT + kt)*64 + l)*8 + jj   -> consumer does 1 coalesced b128/lane
extern "C" __global__ void __launch_bounds__(256)
prep_frag(const float* __restrict__ eWih0, const float* __restrict__ eWhh0,
          const float* __restrict__ eWih1, const float* __restrict__ eWhh1,
          const float* __restrict__ dWih0, const float* __restrict__ dWhh0,
          const float* __restrict__ dWih1, const float* __restrict__ dWhh1,
          unsigned short* __restrict__ ws)
{
  const int idx = blockIdx.x*256 + threadIdx.x;   // one thread -> one (hi,lo) pair
  int i2, hi_base, lo_base, KT;
  const float* Wa; const float* Wb;
  if (idx < L0_SZ)                { i2=idx;                 hi_base=ENC0_HI; lo_base=ENC0_LO; Wa=eWhh0; Wb=eWih0; KT=5; }
  else if (idx < L0_SZ+L1_SZ)     { i2=idx-L0_SZ;           hi_base=ENC1_HI; lo_base=ENC1_LO; Wa=eWih1; Wb=eWhh1; KT=8; }
  else if (idx < 2*L0_SZ+L1_SZ)   { i2=idx-(L0_SZ+L1_SZ);   hi_base=DEC0_HI; lo_base=DEC0_LO; Wa=dWhh0; Wb=dWih0; KT=5; }
  else                            { i2=idx-(2*L0_SZ+L1_SZ); hi_base=DEC1_HI; lo_base=DEC1_LO; Wa=dWih1; Wb=dWhh1; KT=8; }
  const int jj = i2 & 7, l = (i2>>3)&63, tk = i2>>9;
  const int kt = (KT==5) ? (tk%5) : (tk&7);
  const int mt = (KT==5) ? (tk/5) : (tk>>3);
  const int row = mt*16 + (l&15);
  const int k   = kt*32 + ((l>>4)&3)*8 + jj;
  float w;
  if (KT==5) w = (k<128) ? Wa[row*128+k] : ((k<131) ? Wb[row*3 + (k-128)] : 0.f);
  else       w = (k<128) ? Wa[row*128+k] : Wb[row*128 + (k-128)];
  const unsigned short hi = f2bf(w);
  ws[hi_base + i2] = hi;
  ws[lo_base + i2] = f2bf(w - bf2f(hi));
}

// ---------------- fused LSTM: NB=32/block, 4 waves, 3 blocks/CU target ------
extern "C" __global__ void __launch_bounds__(TPB, 3)
lstm_mfma(const float* __restrict__ x,
          const unsigned short* __restrict__ wf,
          const float* __restrict__ enc_b0, const float* __restrict__ enc_b1,
          const float* __restrict__ dec_b0, const float* __restrict__ dec_b1,
          const float* __restrict__ fc_W,  const float* __restrict__ fc_b,
          float* __restrict__ out)
{
  // h in B-frag layout: element (n,k) at n*S + ((k>>3)^(n&7))*8 + (k&7)
  __shared__ unsigned short h0h[NB*S0], h0l[NB*S0];   // K=160 region (x rows 128-130)
  __shared__ unsigned short h1h[NB*S1], h1l[NB*S1];
  __shared__ float bias[2048];
  __shared__ float fcw[6*HID];
  __shared__ float fcb[8];

  const int tid  = threadIdx.x;
  const int w    = tid>>6, l = tid&63;
  const int quad = (l>>4)&3, n15 = l&15, q7 = n15&7;
  const int b0   = blockIdx.x*NB;

  for (int i=tid;i<512;i+=TPB){
    bias[i]=enc_b0[i]; bias[512+i]=enc_b1[i];
    bias[1024+i]=dec_b0[i]; bias[1536+i]=dec_b1[i];
  }
  for (int i=tid;i<6*HID;i+=TPB) fcw[i]=fc_W[i];
  if (tid<6) fcb[tid]=fc_b[tid];
  for (int i=tid;i<NB*S0;i+=TPB){ h0h[i]=0; h0l[i]=0; }
  for (int i=tid;i<NB*S1;i+=TPB){ h1h[i]=0; h1l[i]=0; }
  __syncthreads();

  auto write_x = [&](int t){
    if (tid < 96){
      const int n = tid & 31, c = tid >> 5;
      const float v = x[(size_t)(b0+n)*90 + t*3 + c];
      const int idx = n*S0 + ((16^(n&7))<<3) + c;     // k = 128+c -> block 16
      const unsigned short hi = f2bf(v);
      h0h[idx] = hi; h0l[idx] = f2bf(v - bf2f(hi));
    }
  };
  write_x(0);
  __syncthreads();

  // wave w owns m-tiles mt = g*8 + w*2 + s  (g=gate, s=0,1), i.e. j in [32w,32w+32)
  floatx4 acc[8][2];                 // [g*2+s][nt]
  float c0[2][2][4], c1[2][2][4];    // [s][nt][r]
#pragma unroll
  for (int s=0;s<2;s++)
#pragma unroll
    for (int nt=0;nt<2;nt++)
#pragma unroll
      for (int r=0;r<4;r++){ c0[s][nt][r]=0.f; c1[s][nt][r]=0.f; }

  auto zacc = [&]{
    const floatx4 z = {0.f,0.f,0.f,0.f};
#pragma unroll
    for (int p=0;p<8;p++){ acc[p][0]=z; acc[p][1]=z; }
  };

  // acc += A(kt range) * B(kb = kt-kboff blocks of Bh/Bl)
  auto mv = [&](const unsigned short* __restrict__ Ahi,
                const unsigned short* __restrict__ Alo, int KT,
                int k0, int k1, int kboff,
                const unsigned short* Bh, const unsigned short* Bl, int SS){
#pragma unroll 1
    for (int kt=k0; kt<k1; ++kt){
      const int bo = ((((kt-kboff)*4+quad)^q7)<<3);
      short8 bh[2], bl[2];
#pragma unroll
      for (int nt=0;nt<2;nt++){
        const int ro = (nt*16+n15)*SS + bo;
        bh[nt] = *(const short8*)(Bh + ro);
        bl[nt] = *(const short8*)(Bl + ro);
      }
#pragma unroll
      for (int p=0;p<8;p++){
        const int mt = (p>>1)*8 + w*2 + (p&1);
        const int ao = ((mt*KT + kt)*64 + l)*8;
        const short8 ah = *(const short8*)(Ahi + ao);
        const short8 al = *(const short8*)(Alo + ao);
        acc[p][0] = __builtin_amdgcn_mfma_f32_16x16x32_bf16(ah, bh[0], acc[p][0],0,0,0);
        acc[p][1] = __builtin_amdgcn_mfma_f32_16x16x32_bf16(ah, bh[1], acc[p][1],0,0,0);
        acc[p][0] = __builtin_amdgcn_mfma_f32_16x16x32_bf16(ah, bl[0], acc[p][0],0,0,0);
        acc[p][1] = __builtin_amdgcn_mfma_f32_16x16x32_bf16(ah, bl[1], acc[p][1],0,0,0);
        acc[p][0] = __builtin_amdgcn_mfma_f32_16x16x32_bf16(al, bh[0], acc[p][0],0,0,0);
        acc[p][1] = __builtin_amdgcn_mfma_f32_16x16x32_bf16(al, bh[1], acc[p][1],0,0,0);
      }
    }
  };

  // activations in-register; barrier, then packed b64 h-writes
  auto cell_update = [&](float (&cst)[2][2][4], int boff,
                         unsigned short* Hh, unsigned short* Hl, int SS){
    float hv[2][2][4];
#pragma unroll
    for (int s=0;s<2;s++)
#pragma unroll
      for (int nt=0;nt<2;nt++)
#pragma unroll
        for (int r=0;r<4;r++){
          const int j = (w*2+s)*16 + quad*4 + r;
          const float i_ = sigm(acc[0+s][nt][r]      + bias[boff       + j]);
          const float f_ = sigm(acc[2+s][nt][r]      + bias[boff + 128 + j]);
          const float g_ = tanh_fast(acc[4+s][nt][r] + bias[boff + 256 + j]);
          const float o_ = sigm(acc[6+s][nt][r]      + bias[boff + 384 + j]);
          const float c  = f_*cst[s][nt][r] + i_*g_;
          cst[s][nt][r] = c;
          hv[s][nt][r]  = o_*tanh_fast(c);
        }
    __syncthreads();                 // all waves done READING old h
#pragma unroll
    for (int s=0;s<2;s++)
#pragma unroll
      for (int nt=0;nt<2;nt++){
        const int jb = (w*2+s)*2 + (quad>>1);        // j>>3
        const int n  = nt*16 + n15;
        const int base = n*SS + ((jb ^ (n&7))<<3) + ((quad&1)<<2);
        ushort4v ph, pl;
#pragma unroll
        for (int r=0;r<4;r++){
          const unsigned short hi = f2bf(hv[s][nt][r]);
          ph[r] = hi;
          pl[r] = f2bf(hv[s][nt][r] - bf2f(hi));
        }
        *(ushort4v*)(Hh + base) = ph;                // ds_write_b64
        *(ushort4v*)(Hl + base) = pl;
      }
  };
  // NOTE: acc index map in cell_update: p = g*2+s with g blocks at p={0,1|2,3|4,5|6,7}

  // -------------------- encoder --------------------
#pragma unroll 1
  for (int t=0; t<TSTEPS; ++t){
    zacc();
    mv(wf+ENC0_HI, wf+ENC0_LO, 5, 0, 5, 0, h0h, h0l, S0);
    cell_update(c0, 0, h0h, h0l, S0);
    if (t+1 < TSTEPS) write_x(t+1);      // x-region disjoint from h writes
    __syncthreads();
    zacc();
    mv(wf+ENC1_HI, wf+ENC1_LO, 8, 0, 4, 0, h0h, h0l, S0);
    mv(wf+ENC1_HI, wf+ENC1_LO, 8, 4, 8, 4, h1h, h1l, S1);
    cell_update(c1, 512, h1h, h1l, S1);
    __syncthreads();
  }
  // h0 x-rows still hold x[:,29,:] == decoder's initial input

  // -------------------- decoder --------------------
#pragma unroll 1
  for (int t=0; t<TSTEPS; ++t){
    zacc();
    mv(wf+DEC0_HI, wf+DEC0_LO, 5, 0, 5, 0, h0h, h0l, S0);
    cell_update(c0, 1024, h0h, h0l, S0);
    __syncthreads();
    zacc();
    mv(wf+DEC1_HI, wf+DEC1_LO, 8, 0, 4, 0, h0h, h0l, S0);
    mv(wf+DEC1_HI, wf+DEC1_LO, 8, 4, 8, 4, h1h, h1l, S1);
    cell_update(c1, 1536, h1h, h1l, S1);
    __syncthreads();

    // FC head: stats[6][32] = fcW @ h1 + fcb; mu fed back into h0 x-rows
    if (tid < 192){
      const int n = tid & 31, oi = tid >> 5;
      float s = fcb[oi];
#pragma unroll 4
      for (int blk=0; blk<16; ++blk){
        const int ro = n*S1 + ((blk^(n&7))<<3);
        const short8 hh = *(const short8*)(h1h + ro);
        const short8 hl = *(const short8*)(h1l + ro);
#pragma unroll
        for (int jj=0;jj<8;++jj)
          s += fcw[oi*HID + blk*8 + jj] *
               (bf2f((unsigned short)hh[jj]) + bf2f((unsigned short)hl[jj]));
      }
      const size_t off = (size_t)(b0+n)*90 + (size_t)t*3;
      if (oi < 3){
        out[off + oi] = s;
        const int idx = n*S0 + ((16^(n&7))<<3) + oi;  // k = 128+oi
        const unsigned short hi = f2bf(s);
        h0h[idx] = hi; h0l[idx] = f2bf(s - bf2f(hi));
      } else {
        out[MU_OFF + off + (oi-3)] = s;
      }
    }
    __syncthreads();
  }
}

extern "C" void kernel_launch(void* const* d_in, const int* in_sizes, int n_in,
                              void* d_out, int out_size, void* d_ws, size_t ws_size,
                              hipStream_t stream) {
  const float* x        = (const float*)d_in[0];
  const float* enc_Wih0 = (const float*)d_in[1];
  const float* enc_Whh0 = (const float*)d_in[2];
  const float* enc_b0   = (const float*)d_in[3];
  const float* enc_Wih1 = (const float*)d_in[4];
  const float* enc_Whh1 = (const float*)d_in[5];
  const float* enc_b1   = (const float*)d_in[6];
  const float* dec_Wih0 = (const float*)d_in[7];
  const float* dec_Whh0 = (const float*)d_in[8];
  const float* dec_b0   = (const float*)d_in[9];
  const float* dec_Wih1 = (const float*)d_in[10];
  const float* dec_Whh1 = (const float*)d_in[11];
  const float* dec_b1   = (const float*)d_in[12];
  const float* fc_W     = (const float*)d_in[13];
  const float* fc_b     = (const float*)d_in[14];
  unsigned short* ws = (unsigned short*)d_ws;
  float* out = (float*)d_out;

  // 425,984 (hi,lo) pairs -> exactly 1664 blocks of 256
  prep_frag<<<1664, 256, 0, stream>>>(
      enc_Wih0, enc_Whh0, enc_Wih1, enc_Whh1,
      dec_Wih0, dec_Whh0, dec_Wih1, dec_Whh1, ws);

  lstm_mfma<<<NBLK, TPB, 0, stream>>>(
      x, ws, enc_b0, enc_b1, dec_b0, dec_b1, fc_W, fc_b, out);
}